// Round 3
// baseline (363.947 us; speedup 1.0000x reference)
//
#include <hip/hip_runtime.h>
#include <math.h>

// EMA along T: y[0]=x[0]; y[t] = (1-a)*y[t-1] + a*x[t], a=0.01.
//
// SINGLE-PASS chunked scan with decoupled lookback, exploiting EMA
// forgetting: decay^(64*32) ~ 1.2e-9 (far below the accepted fp32 absmax),
// so each chunk's carry-in needs only the previous W=32 chunk-local sums.
// Per block: (A) read chunk once from HBM, compute local EMA sum;
// (B) publish sum + release flag; (C) spin on the W predecessor flags
// (grid is FULLY co-resident: 1024 blocks x 128 thr = 2048 waves, 0 LDS,
// low VGPR -> no dispatch-order assumption, no deadlock); (D) fold carry;
// (E) apply, re-reading the chunk from L3 (x = 128 MB < 256 MB L3; out is
// NT-stored so it never evicts x). HBM traffic ~256 MB vs 384 MB for the
// 2-kernel version, and no grid-wide barrier between phases.

namespace {
constexpr int B = 8;
constexpr int T = 8192;
constexpr int C = 512;
constexpr float ALPHA = 0.01f;
constexpr float DECAY = 1.0f - ALPHA;   // 0.99
constexpr int S4 = C / 4;               // float4 per timestep = 128
constexpr int TPB = S4;                 // 128 threads, 4 channels each
constexpr int CHUNK = 64;               // timesteps per block
constexpr int K = T / CHUNK;            // 128 chunks -> grid (128,8)
constexpr int W = 32;                   // lookback: 0.99^2048 ~ 1.2e-9
constexpr int NFLAGS = K * B;           // 1024

typedef float f32x4 __attribute__((ext_vector_type(4)));

__device__ __forceinline__ void ema_step(float4& y, const float4 v) {
    y.x = DECAY * y.x + ALPHA * v.x;
    y.y = DECAY * y.y + ALPHA * v.y;
    y.z = DECAY * y.z + ALPHA * v.z;
    y.w = DECAY * y.w + ALPHA * v.w;
}
}

// Flags are in poisoned workspace -> must be zeroed every launch.
__global__ __launch_bounds__(1024) void ema_zero_flags(unsigned int* flags) {
    flags[threadIdx.x] = 0u;
}

__global__ __launch_bounds__(TPB) void ema_onepass(const float* __restrict__ x,
                                                   float* __restrict__ out,
                                                   float* __restrict__ ends,
                                                   unsigned int* __restrict__ flags,
                                                   float dC) {
    const int k = blockIdx.x;
    const int b = blockIdx.y;
    const int tid = threadIdx.x;
    const size_t base4 = (size_t)(b * T + k * CHUNK) * S4 + tid;
    const float4* xp = reinterpret_cast<const float4*>(x) + base4;

    // ---- Pass A: local EMA sum of this chunk (single HBM read of x).
    // k==0 starts from the true init: y_pre = x[0] => y[0] = x[0].
    float4 y;
    if (k == 0) {
        y = xp[0];
    } else {
        y = make_float4(0.f, 0.f, 0.f, 0.f);
    }
#pragma unroll 8
    for (int t = 0; t < CHUNK; ++t) {
        float4 v = xp[(size_t)t * S4];
        ema_step(y, v);
    }

    // ---- Publish local sum, then release the flag.
    float4* ep = reinterpret_cast<float4*>(ends) + (size_t)b * K * S4;
    ep[(size_t)k * S4 + tid] = y;
    __threadfence();        // make ends stores device-visible
    __syncthreads();        // all threads have fenced
    if (tid == 0) {
        __hip_atomic_store(&flags[b * K + k], 1u,
                           __ATOMIC_RELEASE, __HIP_MEMORY_SCOPE_AGENT);
    }

    // ---- Carry-in via bounded lookback fold.
    if (k == 0) {
        y = xp[0];  // true init again for the apply pass
    } else {
        const int m0 = (k > W) ? (k - W) : 0;   // exact for k <= W
        const int cnt = k - m0;                 // <= 32
        if (tid < cnt) {
            // Relaxed agent-scope polls bypass L1 and see remote updates;
            // the acquire ordering is provided by the fence below.
            while (__hip_atomic_load(&flags[b * K + m0 + tid],
                                     __ATOMIC_RELAXED,
                                     __HIP_MEMORY_SCOPE_AGENT) == 0u) {
                __builtin_amdgcn_s_sleep(8);
            }
        }
        __syncthreads();
        __threadfence();    // acquire: subsequent loads see published ends
        y = make_float4(0.f, 0.f, 0.f, 0.f);
#pragma unroll 8
        for (int m = m0; m < k; ++m) {
            float4 e = ep[(size_t)m * S4 + tid];
            y.x = dC * y.x + e.x;
            y.y = dC * y.y + e.y;
            y.z = dC * y.z + e.z;
            y.w = dC * y.w + e.w;
        }
    }

    // ---- Apply: re-read chunk (L3-resident) and stream outputs (NT).
    float4* op = reinterpret_cast<float4*>(out) + base4;
#pragma unroll 8
    for (int t = 0; t < CHUNK; ++t) {
        float4 v = xp[(size_t)t * S4];
        ema_step(y, v);
        __builtin_nontemporal_store(*reinterpret_cast<const f32x4*>(&y),
                                    reinterpret_cast<f32x4*>(op + (size_t)t * S4));
    }
}

// Exact but slow fallback if ws is too small (one block per batch).
__global__ __launch_bounds__(TPB) void ema_seq_kernel(const float* __restrict__ x,
                                                      float* __restrict__ out) {
    const int b = blockIdx.x;
    const int tid = threadIdx.x;
    const float4* xp = reinterpret_cast<const float4*>(x) + (size_t)b * T * S4 + tid;
    float4* op = reinterpret_cast<float4*>(out) + (size_t)b * T * S4 + tid;
    float4 y = xp[0];
    for (int t = 0; t < T; ++t) {
        float4 v = xp[(size_t)t * S4];
        ema_step(y, v);
        op[(size_t)t * S4] = y;
    }
}

extern "C" void kernel_launch(void* const* d_in, const int* in_sizes, int n_in,
                              void* d_out, int out_size, void* d_ws, size_t ws_size,
                              hipStream_t stream) {
    (void)in_sizes; (void)n_in; (void)out_size;
    const float* x = reinterpret_cast<const float*>(d_in[0]);
    float* out = reinterpret_cast<float*>(d_out);

    const size_t ends_bytes = (size_t)B * K * C * sizeof(float);   // 2 MB
    const size_t need = ends_bytes + NFLAGS * sizeof(unsigned int);

    if (ws_size >= need) {
        float* ends = reinterpret_cast<float*>(d_ws);
        unsigned int* flags =
            reinterpret_cast<unsigned int*>(reinterpret_cast<char*>(d_ws) + ends_bytes);
        const float dC = (float)pow((double)DECAY, (double)CHUNK);
        ema_zero_flags<<<dim3(1), dim3(NFLAGS), 0, stream>>>(flags);
        ema_onepass<<<dim3(K, B), dim3(TPB), 0, stream>>>(x, out, ends, flags, dC);
    } else {
        ema_seq_kernel<<<dim3(B), dim3(TPB), 0, stream>>>(x, out);
    }
}

// Round 4
// 254.921 us; speedup vs baseline: 1.4277x; 1.4277x over previous
//
#include <hip/hip_runtime.h>
#include <math.h>

// EMA along T: y[0]=x[0]; y[t] = (1-a)*y[t-1] + a*x[t], a=0.01.
//
// 2-phase chunked scan exploiting EMA forgetting. CHUNK=32 -> K=256 ->
// 2048 blocks -> 16 waves/CU in both streaming phases (round 2's CHUNK=64
// gave only 8 waves/CU; the harness fill kernels prove ~84% peak needs
// full-occupancy streaming). Carry-in uses a bounded W=32-chunk lookback
// (1024 timesteps; truncation 0.99^1024 ~ 3.4e-5, ~1000x below the
// accepted absmax; EXACT for k<=W since ends[0] holds the true S_0).
// Round-3 counters proved the phase-2 x re-read L3-hits (FETCH 139MB for
// a 2x-read kernel) and NT out-stores keep x resident -> HBM traffic is
// already at the ~256MB algorithmic floor; this round buys BW efficiency.
// (Round 3 also proved per-block cross-XCD fences/spins run at 1.3 TB/s
// -- single-pass decoupled lookback is a dead end on this chip.)

namespace {
constexpr int B = 8;
constexpr int T = 8192;
constexpr int C = 512;
constexpr float ALPHA = 0.01f;
constexpr float DECAY = 1.0f - ALPHA;   // 0.99
constexpr int S4 = C / 4;               // float4 per timestep = 128
constexpr int TPB = S4;                 // 128 threads, 4 channels each
constexpr int CHUNK = 32;               // timesteps per block
constexpr int K = T / CHUNK;            // 256 chunks -> grid (256,8) = 2048 blocks
constexpr int W = 32;                   // lookback chunks: 0.99^1024 ~ 3.4e-5

typedef float f32x4 __attribute__((ext_vector_type(4)));

__device__ __forceinline__ void ema_step(float4& y, const float4 v) {
    y.x = DECAY * y.x + ALPHA * v.x;
    y.y = DECAY * y.y + ALPHA * v.y;
    y.z = DECAY * y.z + ALPHA * v.z;
    y.w = DECAY * y.w + ALPHA * v.w;
}
}

// Phase 1: per-chunk local EMA end-state. k==0 starts from the true init
// (y_pre = x[0] => y[0] = x[0]), so ends[0] holds the TRUE running state
// S_0; k>0 chunks start from 0 and produce local sums L_k.
__global__ __launch_bounds__(TPB) void ema_ends(const float* __restrict__ x,
                                                float* __restrict__ ends) {
    const int k = blockIdx.x;
    const int b = blockIdx.y;
    const int tid = threadIdx.x;
    const float4* xp = reinterpret_cast<const float4*>(x) +
                       (size_t)(b * T + k * CHUNK) * S4 + tid;
    float4 y;
    if (k == 0) {
        y = xp[0];
    } else {
        y = make_float4(0.f, 0.f, 0.f, 0.f);
    }
#pragma unroll 16
    for (int t = 0; t < CHUNK; ++t) {
        float4 v = xp[(size_t)t * S4];
        ema_step(y, v);
    }
    reinterpret_cast<float4*>(ends)[(size_t)(b * K + k) * S4 + tid] = y;
}

// Phase 2: bounded-window carry fold + apply.
// Carry: S_{k-1} = sum_{m=m0}^{k-1} dC^{k-1-m} E_m, m0 = max(0, k-W).
// Common case (k>W, 224/256 of blocks): two parallel 16-step FMA chains
// combined by dC^16 — halves the dependent-chain latency. ends is 4 MB ->
// L2-resident. Apply re-reads x (L3-hit) and NT-streams out.
__global__ __launch_bounds__(TPB) void ema_fold_apply(const float* __restrict__ x,
                                                      const float* __restrict__ ends,
                                                      float* __restrict__ out,
                                                      float dC, float dC16) {
    const int k = blockIdx.x;
    const int b = blockIdx.y;
    const int tid = threadIdx.x;
    const size_t base4 = (size_t)(b * T + k * CHUNK) * S4 + tid;
    const float4* xp = reinterpret_cast<const float4*>(x) + base4;
    float4* op = reinterpret_cast<float4*>(out) + base4;
    const float4* ep = reinterpret_cast<const float4*>(ends) +
                       (size_t)b * K * S4 + tid;

    float4 y;
    if (k == 0) {
        y = xp[0];  // true init trick (see phase 1)
    } else if (k <= W) {
        // exact fold from E_0 (= true S_0)
        y = make_float4(0.f, 0.f, 0.f, 0.f);
        for (int m = 0; m < k; ++m) {
            float4 e = ep[(size_t)m * S4];
            y.x = dC * y.x + e.x;
            y.y = dC * y.y + e.y;
            y.z = dC * y.z + e.z;
            y.w = dC * y.w + e.w;
        }
    } else {
        const int m0 = k - W;
        float4 ylo = make_float4(0.f, 0.f, 0.f, 0.f);
        float4 yhi = make_float4(0.f, 0.f, 0.f, 0.f);
#pragma unroll
        for (int i = 0; i < W / 2; ++i) {
            float4 elo = ep[(size_t)(m0 + i) * S4];
            float4 ehi = ep[(size_t)(m0 + W / 2 + i) * S4];
            ylo.x = dC * ylo.x + elo.x;  yhi.x = dC * yhi.x + ehi.x;
            ylo.y = dC * ylo.y + elo.y;  yhi.y = dC * yhi.y + ehi.y;
            ylo.z = dC * ylo.z + elo.z;  yhi.z = dC * yhi.z + ehi.z;
            ylo.w = dC * ylo.w + elo.w;  yhi.w = dC * yhi.w + ehi.w;
        }
        y.x = dC16 * ylo.x + yhi.x;
        y.y = dC16 * ylo.y + yhi.y;
        y.z = dC16 * ylo.z + yhi.z;
        y.w = dC16 * ylo.w + yhi.w;
    }
#pragma unroll 16
    for (int t = 0; t < CHUNK; ++t) {
        float4 v = xp[(size_t)t * S4];
        ema_step(y, v);
        // NT store: out is never re-read; keeps x resident in L3 for this
        // kernel's own read stream (verified round 3: FETCH 139MB).
        __builtin_nontemporal_store(*reinterpret_cast<const f32x4*>(&y),
                                    reinterpret_cast<f32x4*>(op + (size_t)t * S4));
    }
}

// Exact but slow fallback if ws is too small (one block per batch).
__global__ __launch_bounds__(TPB) void ema_seq_kernel(const float* __restrict__ x,
                                                      float* __restrict__ out) {
    const int b = blockIdx.x;
    const int tid = threadIdx.x;
    const float4* xp = reinterpret_cast<const float4*>(x) + (size_t)b * T * S4 + tid;
    float4* op = reinterpret_cast<float4*>(out) + (size_t)b * T * S4 + tid;
    float4 y = xp[0];
    for (int t = 0; t < T; ++t) {
        float4 v = xp[(size_t)t * S4];
        ema_step(y, v);
        op[(size_t)t * S4] = y;
    }
}

extern "C" void kernel_launch(void* const* d_in, const int* in_sizes, int n_in,
                              void* d_out, int out_size, void* d_ws, size_t ws_size,
                              hipStream_t stream) {
    (void)in_sizes; (void)n_in; (void)out_size;
    const float* x = reinterpret_cast<const float*>(d_in[0]);
    float* out = reinterpret_cast<float*>(d_out);

    const size_t need = (size_t)B * K * C * sizeof(float);  // 4 MB
    if (ws_size >= need) {
        float* ends = reinterpret_cast<float*>(d_ws);
        const float dC = (float)pow((double)DECAY, (double)CHUNK);
        const float dC16 = (float)pow((double)DECAY, (double)(CHUNK * (W / 2)));
        ema_ends<<<dim3(K, B), dim3(TPB), 0, stream>>>(x, ends);
        ema_fold_apply<<<dim3(K, B), dim3(TPB), 0, stream>>>(x, ends, out, dC, dC16);
    } else {
        ema_seq_kernel<<<dim3(B), dim3(TPB), 0, stream>>>(x, out);
    }
}